// Round 1
// baseline (92.859 us; speedup 1.0000x reference)
//
#include <hip/hip_runtime.h>
#include <hip/hip_bf16.h>
#include <stdint.h>

#define BB 8
#define NN 2048
#define CC 128
#define OO 128

typedef __attribute__((ext_vector_type(8))) short bf16x8;
typedef __attribute__((ext_vector_type(4))) float f32x4;
typedef __attribute__((ext_vector_type(4))) int i32x4;
typedef unsigned int u32;
typedef unsigned short u16;

__device__ __forceinline__ u16 f2bf(float f) {
    union { float f; u32 u; } v; v.f = f;
    u32 r = v.u + 0x7FFFu + ((v.u >> 16) & 1u);
    return (u16)(r >> 16);
}
__device__ __forceinline__ float bf2f(u16 h) {
    union { u32 u; float f; } v; v.u = ((u32)h) << 16;
    return v.f;
}
// async global->LDS 16B copy: LDS dest = wave-uniform base + lane*16,
// global src is per-lane (this is where the swizzle lives).
__device__ __forceinline__ void gl_lds16(const u16* g, u16* l) {
    __builtin_amdgcn_global_load_lds(
        (__attribute__((address_space(1))) void*)(uintptr_t)g,
        (__attribute__((address_space(3))) void*)l, 16, 0, 0);
}

// ---------------------------------------------------------------------------
// Kernel 1: fused precompute.
//   sj[b][n] = x[b][n]·w1 + b_fc   (bias folded)
//   sk[b][n] = x[b][n]·w2
//   Yt[b][o][k] = (x @ W_lin)[k][o]   stored transposed, bf16
// grid = B * N/64 = 256 blocks, 256 threads.
// ---------------------------------------------------------------------------
__global__ __launch_bounds__(256) void precompute_kernel(
    const float* __restrict__ x, const float* __restrict__ W_fc,
    const float* __restrict__ b_fc, const float* __restrict__ W_lin,
    float* __restrict__ sj, float* __restrict__ sk, u16* __restrict__ Yt)
{
    __shared__ __align__(16) float xs[64][132];   // +4 pad: bank spread
    __shared__ __align__(16) u16  yt[128][72];    // +8 pad: 144B rows, 16B-aligned

    const int t  = threadIdx.x;
    const int b  = blockIdx.x >> 5;
    const int k0 = (blockIdx.x & 31) << 6;

    // stage x[k0..k0+64][0..128] (f32, coalesced float4)
    const float* xbase = x + (size_t)(b * NN + k0) * CC;
    #pragma unroll
    for (int i = 0; i < 8; ++i) {
        int f = t + i * 256;
        int row = f >> 5, c4 = f & 31;
        f32x4 v = *(const f32x4*)(xbase + row * CC + c4 * 4);
        *(f32x4*)&xs[row][c4 * 4] = v;
    }
    __syncthreads();

    // sj / sk: 4 lanes per row
    {
        int g = t >> 2, q = t & 3;
        float p1 = 0.f, p2 = 0.f;
        #pragma unroll
        for (int i = 0; i < 8; ++i) {
            f32x4 xv = *(const f32x4*)&xs[g][q * 32 + i * 4];
            f32x4 w1 = *(const f32x4*)(W_fc + q * 32 + i * 4);
            f32x4 w2 = *(const f32x4*)(W_fc + CC + q * 32 + i * 4);
            p1 += xv[0]*w1[0] + xv[1]*w1[1] + xv[2]*w1[2] + xv[3]*w1[3];
            p2 += xv[0]*w2[0] + xv[1]*w2[1] + xv[2]*w2[2] + xv[3]*w2[3];
        }
        p1 += __shfl_xor(p1, 1); p1 += __shfl_xor(p1, 2);
        p2 += __shfl_xor(p2, 1); p2 += __shfl_xor(p2, 2);
        if (q == 0) {
            sj[b * NN + k0 + g] = p1 + b_fc[0];
            sk[b * NN + k0 + g] = p2;
        }
    }

    // Y = x @ W_lin for this k-tile. thread: o = t&127, k-half = t>>7.
    {
        int o = t & 127, kh = t >> 7;
        float acc[32];
        #pragma unroll
        for (int i = 0; i < 32; ++i) acc[i] = 0.f;
        for (int c4 = 0; c4 < 32; ++c4) {
            float w0 = W_lin[(c4 * 4 + 0) * OO + o];
            float w1 = W_lin[(c4 * 4 + 1) * OO + o];
            float w2 = W_lin[(c4 * 4 + 2) * OO + o];
            float w3 = W_lin[(c4 * 4 + 3) * OO + o];
            #pragma unroll
            for (int i = 0; i < 32; ++i) {
                f32x4 xv = *(const f32x4*)&xs[kh * 32 + i][c4 * 4];
                acc[i] += xv[0]*w0 + xv[1]*w1 + xv[2]*w2 + xv[3]*w3;
            }
        }
        #pragma unroll
        for (int c8 = 0; c8 < 4; ++c8) {
            bf16x8 pk;
            #pragma unroll
            for (int e = 0; e < 8; ++e) pk[e] = (short)f2bf(acc[c8 * 8 + e]);
            *(bf16x8*)&yt[o][kh * 32 + c8 * 8] = pk;
        }
    }
    __syncthreads();

    // coalesced transposed store: Yt[b][o][k0 + ...]
    #pragma unroll
    for (int p = 0; p < 4; ++p) {
        int idx = t + p * 256;
        int o = idx >> 3, c8 = idx & 7;
        bf16x8 v = *(const bf16x8*)&yt[o][c8 * 8];
        *(bf16x8*)(Yt + (size_t)(b * OO + o) * NN + k0 + c8 * 8) = v;
    }
}

// ---------------------------------------------------------------------------
// Kernel 2: main fused aggregation.
//   P[j][k] = adj ? sigmoid(sj[j] + sk[k]) : 0   (bf16)
//   V[j][o] = sum_k P[j][k] * Yt[o][k]           (MFMA, f32 accum)
//   out[j][o] = V / rowsum(P) + b_lin[o]
// grid = B * N/32 = 512 blocks, 256 threads (4 waves).
// LDS chunk swizzle: 16B chunk (row, kc) lives at u = row*16 + (kc ^ (row&15)).
// ---------------------------------------------------------------------------
__global__ __launch_bounds__(256) void graphconv_main(
    const int* __restrict__ adj, const float* __restrict__ sj,
    const float* __restrict__ sk, const u16* __restrict__ Yt,
    const float* __restrict__ b_lin, float* __restrict__ out)
{
    __shared__ __align__(16) u16 ybuf[16384];  // 128 o rows x 16 chunks x 8 elems
    __shared__ __align__(16) u16 pbuf[4096];   // 32 j rows x 16 chunks x 8 elems
    __shared__ float Sld[32];

    const int t  = threadIdx.x;
    const int l  = t & 63, w = t >> 6;
    const int sw = l & 15, kg = l >> 4;
    const int b  = blockIdx.x >> 6;
    const int j0 = (blockIdx.x & 63) << 5;
    const int rt = w & 1;            // row-tile (16 rows)
    const int cb = (w >> 1) << 2;    // col-tile base (4 tiles of 16)

    // P-compute mapping: thread -> row pj, 16 consecutive k at pk0
    const int pj  = t >> 3;
    const int pk0 = (t & 7) << 4;
    const float sjr = sj[b * NN + j0 + pj];   // b_fc folded in

    // Y staging: linear LDS dest, inverse-swizzled per-lane global source
    u32 yoff[8]; u16* ydst[8];
    #pragma unroll
    for (int i = 0; i < 8; ++i) {
        int u = (w * 8 + i) * 64 + l;
        int o = u >> 4;
        int kc = (u & 15) ^ (o & 15);
        yoff[i] = (u32)(b * OO + o) * NN + kc * 8;
        ydst[i] = ybuf + (size_t)(w * 8 + i) * 512;   // wave-uniform
    }

    const i32x4* adjbase = (const i32x4*)(adj + (size_t)(b * NN + j0 + pj) * NN + pk0);

    f32x4 acc[4];
    #pragma unroll
    for (int ct = 0; ct < 4; ++ct) acc[ct] = (f32x4){0.f, 0.f, 0.f, 0.f};
    float Srun = 0.f;

    i32x4 a_cur[4]; f32x4 s_cur[4];
    {
        #pragma unroll
        for (int q = 0; q < 4; ++q) a_cur[q] = adjbase[q];
        const float* sp = sk + b * NN + pk0;
        #pragma unroll
        for (int q = 0; q < 4; ++q) s_cur[q] = *(const f32x4*)(sp + q * 4);
    }

    for (int kt = 0; kt < 16; ++kt) {
        const int k0 = kt << 7;
        __syncthreads();                      // prev MFMA reads done
        // stage Y tile (async, drained by next barrier)
        #pragma unroll
        for (int i = 0; i < 8; ++i)
            gl_lds16(Yt + yoff[i] + k0, ydst[i]);
        // prefetch next adj/sk tile into registers
        const int ktn = (kt < 15) ? kt + 1 : 15;
        i32x4 a_nxt[4]; f32x4 s_nxt[4];
        {
            const i32x4* ap = adjbase + (size_t)ktn * 32;
            #pragma unroll
            for (int q = 0; q < 4; ++q) a_nxt[q] = ap[q];
            const float* sp = sk + b * NN + (ktn << 7) + pk0;
            #pragma unroll
            for (int q = 0; q < 4; ++q) s_nxt[q] = *(const f32x4*)(sp + q * 4);
        }
        // P = masked sigmoid, pack bf16, rowsum
        u16 pb[16];
        float ps = 0.f;
        #pragma unroll
        for (int q = 0; q < 4; ++q) {
            #pragma unroll
            for (int e = 0; e < 4; ++e) {
                float z  = sjr + s_cur[q][e];
                float sg = __builtin_amdgcn_rcpf(1.0f + __expf(-z));
                float pv = a_cur[q][e] ? sg : 0.0f;
                u16 h = f2bf(pv);
                pb[q * 4 + e] = h;
                ps += bf2f(h);
            }
        }
        ps += __shfl_xor(ps, 1);
        ps += __shfl_xor(ps, 2);
        ps += __shfl_xor(ps, 4);
        Srun += ps;                            // same value across the 8-lane group
        {
            int kcA = (t & 7) * 2;
            bf16x8 vA, vB;
            #pragma unroll
            for (int e = 0; e < 8; ++e) { vA[e] = (short)pb[e]; vB[e] = (short)pb[8 + e]; }
            int uA = pj * 16 + (kcA ^ (pj & 15));
            int uB = pj * 16 + ((kcA + 1) ^ (pj & 15));
            *(bf16x8*)&pbuf[uA * 8] = vA;
            *(bf16x8*)&pbuf[uB * 8] = vB;
        }
        __syncthreads();                      // P visible, Y staged (vmcnt0)
        // MFMA: 16 per wave (4 k-steps x 4 col-tiles)
        #pragma unroll
        for (int kk = 0; kk < 4; ++kk) {
            const int kc = kk * 4 + kg;
            const int uA = (rt * 16 + sw) * 16 + (kc ^ sw);
            bf16x8 af = *(const bf16x8*)&pbuf[uA * 8];
            #pragma unroll
            for (int ct = 0; ct < 4; ++ct) {
                const int o  = (cb + ct) * 16 + sw;
                const int uB = o * 16 + (kc ^ sw);
                bf16x8 bfv = *(const bf16x8*)&ybuf[uB * 8];
                acc[ct] = __builtin_amdgcn_mfma_f32_16x16x32_bf16(af, bfv, acc[ct], 0, 0, 0);
            }
        }
        #pragma unroll
        for (int q = 0; q < 4; ++q) { a_cur[q] = a_nxt[q]; s_cur[q] = s_nxt[q]; }
    }

    if ((t & 7) == 0) Sld[pj] = Srun;
    __syncthreads();

    // epilogue: scale by 1/rowsum, add bias, store f32
    float rinv[4];
    #pragma unroll
    for (int i = 0; i < 4; ++i) rinv[i] = 1.0f / Sld[rt * 16 + kg * 4 + i];
    #pragma unroll
    for (int ct = 0; ct < 4; ++ct) {
        const int col = (cb + ct) * 16 + sw;
        const float bl = b_lin[col];
        #pragma unroll
        for (int i = 0; i < 4; ++i) {
            size_t row = (size_t)(b * NN + j0 + rt * 16 + kg * 4 + i);
            out[row * OO + col] = acc[ct][i] * rinv[i] + bl;
        }
    }
}

extern "C" void kernel_launch(void* const* d_in, const int* in_sizes, int n_in,
                              void* d_out, int out_size, void* d_ws, size_t ws_size,
                              hipStream_t stream) {
    const float* x     = (const float*)d_in[0];
    const int*   adj   = (const int*)d_in[1];
    const float* W_fc  = (const float*)d_in[2];
    const float* b_fc  = (const float*)d_in[3];
    const float* W_lin = (const float*)d_in[4];
    const float* b_lin = (const float*)d_in[5];
    float* out = (float*)d_out;

    // workspace layout: Yt (bf16, 4MB) | sj (64KB) | sk (64KB)
    u16*   Yt = (u16*)d_ws;
    float* sj = (float*)((char*)d_ws + (size_t)BB * OO * NN * sizeof(u16));
    float* sk = sj + BB * NN;

    precompute_kernel<<<BB * (NN / 64), 256, 0, stream>>>(x, W_fc, b_fc, W_lin, sj, sk, Yt);
    graphconv_main<<<BB * (NN / 32), 256, 0, stream>>>(adj, sj, sk, Yt, b_lin, out);
}

// Round 2
// 65.079 us; speedup vs baseline: 1.4269x; 1.4269x over previous
//
#include <hip/hip_runtime.h>
#include <stdint.h>

#define BB 8
#define NN 2048
#define CC 128
#define OO 128

typedef __attribute__((ext_vector_type(8))) short bf16x8;
typedef __attribute__((ext_vector_type(4))) float f32x4;
typedef __attribute__((ext_vector_type(4))) int i32x4;
typedef __attribute__((ext_vector_type(4))) unsigned int u32x4;
typedef __attribute__((ext_vector_type(4))) unsigned short u16x4;
typedef unsigned int u32;
typedef unsigned short u16;

__device__ __forceinline__ u16 f2bf(float f) {
    union { float f; u32 u; } v; v.f = f;
    u32 r = v.u + 0x7FFFu + ((v.u >> 16) & 1u);
    return (u16)(r >> 16);
}

// async global->LDS 16B: LDS dest wave-uniform base + lane*16; swizzle lives
// in the per-lane global source address (m104/m173 rule).
__device__ __forceinline__ void gl_lds16(const u16* g, u16* l) {
    __builtin_amdgcn_global_load_lds(
        (__attribute__((address_space(1))) void*)(uintptr_t)g,
        (__attribute__((address_space(3))) void*)l, 16, 0, 0);
}

// ---------------------------------------------------------------------------
// Kernel 1: fused precompute.
//   sj[b][n] = x[b][n]·w1 + b_fc ; sk[b][n] = x[b][n]·w2
//   Yt[b][o][k] = (x @ W_lin)^T  (bf16)
// 512 blocks x 256 thr; k-tile 32. Register-blocked 4k x 4o Y-GEMM:
// 128 ds_read_b128/thread (was 1024).
// ---------------------------------------------------------------------------
__global__ __launch_bounds__(256, 2) void precompute_kernel(
    const float* __restrict__ x, const float* __restrict__ W_fc,
    const float* __restrict__ b_fc, const float* __restrict__ W_lin,
    float* __restrict__ sj, float* __restrict__ sk, u16* __restrict__ Yt)
{
    __shared__ __align__(16) float xs[32][132];

    const int t  = threadIdx.x;
    const int b  = blockIdx.x >> 6;
    const int k0 = (blockIdx.x & 63) << 5;

    const float* xbase = x + (size_t)(b * NN + k0) * CC;
    #pragma unroll
    for (int i = 0; i < 4; ++i) {
        int f = t + i * 256;
        int row = f >> 5, c4 = f & 31;
        *(f32x4*)&xs[row][c4 * 4] = *(const f32x4*)(xbase + row * CC + c4 * 4);
    }
    __syncthreads();

    // sj / sk: 8 lanes per row
    {
        int r = t >> 3, q = t & 7;
        float p1 = 0.f, p2 = 0.f;
        #pragma unroll
        for (int i = 0; i < 4; ++i) {
            f32x4 xv = *(const f32x4*)&xs[r][q * 16 + i * 4];
            f32x4 w1 = *(const f32x4*)(W_fc + q * 16 + i * 4);
            f32x4 w2 = *(const f32x4*)(W_fc + CC + q * 16 + i * 4);
            p1 += xv[0]*w1[0] + xv[1]*w1[1] + xv[2]*w1[2] + xv[3]*w1[3];
            p2 += xv[0]*w2[0] + xv[1]*w2[1] + xv[2]*w2[2] + xv[3]*w2[3];
        }
        p1 += __shfl_xor(p1, 1); p1 += __shfl_xor(p1, 2); p1 += __shfl_xor(p1, 4);
        p2 += __shfl_xor(p2, 1); p2 += __shfl_xor(p2, 2); p2 += __shfl_xor(p2, 4);
        if (q == 0) {
            sj[b * NN + k0 + r] = p1 + b_fc[0];
            sk[b * NN + k0 + r] = p2;
        }
    }

    // Y: thread = (og = t&31 -> 4 o-cols, kq = t>>5 -> 4 k-rows)
    {
        const int og = t & 31, kq = t >> 5;
        f32x4 acc[4];
        #pragma unroll
        for (int r = 0; r < 4; ++r) acc[r] = (f32x4){0.f, 0.f, 0.f, 0.f};
        for (int c4 = 0; c4 < 32; ++c4) {
            f32x4 wv[4];
            #pragma unroll
            for (int cc = 0; cc < 4; ++cc)
                wv[cc] = *(const f32x4*)(W_lin + (c4 * 4 + cc) * OO + og * 4);
            #pragma unroll
            for (int r = 0; r < 4; ++r) {
                f32x4 xv = *(const f32x4*)&xs[kq * 4 + r][c4 * 4];
                #pragma unroll
                for (int cc = 0; cc < 4; ++cc) {
                    acc[r][0] += xv[cc] * wv[cc][0];
                    acc[r][1] += xv[cc] * wv[cc][1];
                    acc[r][2] += xv[cc] * wv[cc][2];
                    acc[r][3] += xv[cc] * wv[cc][3];
                }
            }
        }
        // store Yt[b][o][k0 + kq*4 .. +4), o = og*4+cc  (8B stores; the 8 kq
        // groups of the block complete each 64B line -> L2 merges)
        #pragma unroll
        for (int cc = 0; cc < 4; ++cc) {
            u16x4 h;
            #pragma unroll
            for (int r = 0; r < 4; ++r) h[r] = f2bf(acc[r][cc]);
            *(u16x4*)(Yt + (size_t)(b * OO + og * 4 + cc) * NN + k0 + kq * 4) = h;
        }
    }
}

// ---------------------------------------------------------------------------
// Kernel 2: main fused aggregation, counted-vmcnt pipeline.
//   P[j][k] = adj ? sigmoid(sj[j]+sk[k]) : 0 (bf16), V = P@Y^T (MFMA),
//   out = V/rowsum + b_lin
// 512 blocks (b = bid&7 -> XCD-pinned), 256 thr. ybuf double-buffered;
// per iter: stage(t+1)+adj(t+1) stay in flight across barrier via vmcnt(16).
// Wave w owns o-tile w*32 (no B-read duplication): 16 b128 reads, 16 MFMA.
// ---------------------------------------------------------------------------
__global__ __launch_bounds__(256, 2) void graphconv_main(
    const int* __restrict__ adj, const float* __restrict__ sj,
    const float* __restrict__ sk, const u16* __restrict__ Yt,
    const float* __restrict__ b_lin, float* __restrict__ out)
{
    __shared__ __align__(16) u16 ybuf[2][16384];  // 2 x 128 o-rows x 16 chunks x 8
    __shared__ __align__(16) u16 pbuf[4096];      // 32 j-rows x 16 chunks x 8
    __shared__ float Sld[32];

    const int t  = threadIdx.x;
    const int l  = t & 63, w = t >> 6;
    const int sw = l & 15, kg = l >> 4;
    const int b  = blockIdx.x & 7;            // XCD-pinned batch
    const int j0 = (blockIdx.x >> 3) << 5;

    const int pj  = t >> 3;
    const int pk0 = (t & 7) << 4;
    const float sjr = sj[b * NN + j0 + pj];

    u32 yoff[8];
    #pragma unroll
    for (int i = 0; i < 8; ++i) {
        int u  = (w * 8 + i) * 64 + l;
        int o  = u >> 4;
        int kc = (u & 15) ^ (o & 15);
        yoff[i] = (u32)(b * OO + o) * NN + kc * 8;
    }

    const i32x4* adjbase = (const i32x4*)(adj + (size_t)(b * NN + j0 + pj) * NN + pk0);
    const float* skbase  = sk + b * NN + pk0;

    f32x4 acc[2][2];
    #pragma unroll
    for (int js = 0; js < 2; ++js)
        #pragma unroll
        for (int os = 0; os < 2; ++os) acc[js][os] = (f32x4){0.f, 0.f, 0.f, 0.f};
    float Srun = 0.f;

    // prologue: stage tile0 -> ybuf[0]; load adj/sk tile0
    #pragma unroll
    for (int i = 0; i < 8; ++i)
        gl_lds16(Yt + yoff[i], &ybuf[0][(w * 8 + i) * 512]);
    i32x4 a_cur[4]; f32x4 s_cur[4];
    #pragma unroll
    for (int q = 0; q < 4; ++q) a_cur[q] = adjbase[q];
    #pragma unroll
    for (int q = 0; q < 4; ++q) s_cur[q] = *(const f32x4*)(skbase + q * 4);

    for (int kt = 0; kt < 16; ++kt) {
        const int cur = kt & 1;
        const int ktn = (kt < 15) ? kt + 1 : 15;   // tail: idempotent re-stage keeps vmcnt accounting uniform
        // stage next Y tile into the other buffer (floats across this iter)
        #pragma unroll
        for (int i = 0; i < 8; ++i)
            gl_lds16(Yt + yoff[i] + (ktn << 7), &ybuf[cur ^ 1][(w * 8 + i) * 512]);
        // prefetch next adj/sk into regs (floats too)
        i32x4 a_nxt[4]; f32x4 s_nxt[4];
        #pragma unroll
        for (int q = 0; q < 4; ++q) a_nxt[q] = adjbase[(size_t)ktn * 32 + q];
        #pragma unroll
        for (int q = 0; q < 4; ++q) s_nxt[q] = *(const f32x4*)(skbase + (ktn << 7) + q * 4);

        // P = masked sigmoid; rowsum on unrounded values
        u32 pw[8];
        float ps = 0.f;
        #pragma unroll
        for (int q = 0; q < 4; ++q) {
            u16 h[4];
            #pragma unroll
            for (int e = 0; e < 4; ++e) {
                float z  = sjr + s_cur[q][e];
                float sg = __builtin_amdgcn_rcpf(1.0f + __expf(-z));
                float pv = a_cur[q][e] ? sg : 0.0f;
                ps += pv;
                h[e] = f2bf(pv);
            }
            pw[q * 2]     = (u32)h[0] | ((u32)h[1] << 16);
            pw[q * 2 + 1] = (u32)h[2] | ((u32)h[3] << 16);
        }
        ps += __shfl_xor(ps, 1); ps += __shfl_xor(ps, 2); ps += __shfl_xor(ps, 4);
        Srun += ps;
        {
            int kcA = (t & 7) * 2;
            int uA = pj * 16 + (kcA ^ (pj & 15));
            int uB = pj * 16 + ((kcA + 1) ^ (pj & 15));
            *(u32x4*)&pbuf[uA * 8] = (u32x4){pw[0], pw[1], pw[2], pw[3]};
            *(u32x4*)&pbuf[uB * 8] = (u32x4){pw[4], pw[5], pw[6], pw[7]};
        }

        // counted drain: stage(kt) done (16 younger ops remain in flight)
        asm volatile("s_waitcnt vmcnt(16)" ::: "memory");
        asm volatile("s_waitcnt lgkmcnt(0)" ::: "memory");
        __builtin_amdgcn_s_barrier();
        asm volatile("" ::: "memory");

        // MFMA: wave w -> j 0..31 x o [w*32, w*32+32)
        #pragma unroll
        for (int kk = 0; kk < 4; ++kk) {
            const int kc = kk * 4 + kg;
            bf16x8 af[2], bfr[2];
            #pragma unroll
            for (int js = 0; js < 2; ++js)
                af[js] = *(const bf16x8*)&pbuf[((js * 16 + sw) * 16 + (kc ^ sw)) * 8];
            #pragma unroll
            for (int os = 0; os < 2; ++os) {
                int o = w * 32 + os * 16 + sw;
                bfr[os] = *(const bf16x8*)&ybuf[cur][(o * 16 + (kc ^ sw)) * 8];
            }
            #pragma unroll
            for (int js = 0; js < 2; ++js)
                #pragma unroll
                for (int os = 0; os < 2; ++os)
                    acc[js][os] = __builtin_amdgcn_mfma_f32_16x16x32_bf16(
                        af[js], bfr[os], acc[js][os], 0, 0, 0);
        }

        asm volatile("" ::: "memory");
        __builtin_amdgcn_s_barrier();   // MFMA reads done before next iter's writes
        asm volatile("" ::: "memory");

        #pragma unroll
        for (int q = 0; q < 4; ++q) { a_cur[q] = a_nxt[q]; s_cur[q] = s_nxt[q]; }
    }

    if ((t & 7) == 0) Sld[pj] = Srun;
    __syncthreads();   // also drains the tail junk DMA before kernel end

    #pragma unroll
    for (int js = 0; js < 2; ++js) {
        float rinv[4];
        #pragma unroll
        for (int i = 0; i < 4; ++i) rinv[i] = 1.0f / Sld[js * 16 + kg * 4 + i];
        #pragma unroll
        for (int os = 0; os < 2; ++os) {
            const int col = w * 32 + os * 16 + sw;
            const float bl = b_lin[col];
            #pragma unroll
            for (int i = 0; i < 4; ++i) {
                size_t row = (size_t)(b * NN + j0 + js * 16 + kg * 4 + i);
                out[row * OO + col] = acc[js][os][i] * rinv[i] + bl;
            }
        }
    }
}

extern "C" void kernel_launch(void* const* d_in, const int* in_sizes, int n_in,
                              void* d_out, int out_size, void* d_ws, size_t ws_size,
                              hipStream_t stream) {
    const float* x     = (const float*)d_in[0];
    const int*   adj   = (const int*)d_in[1];
    const float* W_fc  = (const float*)d_in[2];
    const float* b_fc  = (const float*)d_in[3];
    const float* W_lin = (const float*)d_in[4];
    const float* b_lin = (const float*)d_in[5];
    float* out = (float*)d_out;

    // workspace: Yt (bf16, 4MB) | sj (64KB) | sk (64KB)
    u16*   Yt = (u16*)d_ws;
    float* sj = (float*)((char*)d_ws + (size_t)BB * OO * NN * sizeof(u16));
    float* sk = sj + BB * NN;

    precompute_kernel<<<512, 256, 0, stream>>>(x, W_fc, b_fc, W_lin, sj, sk, Yt);
    graphconv_main<<<512, 256, 0, stream>>>(adj, sj, sk, Yt, b_lin, out);
}

// Round 3
// 50.935 us; speedup vs baseline: 1.8231x; 1.2777x over previous
//
#include <hip/hip_runtime.h>
#include <stdint.h>

#define BB 8
#define NN 2048
#define CC 128
#define OO 128

typedef __attribute__((ext_vector_type(8))) short bf16x8;
typedef __attribute__((ext_vector_type(4))) float f32x4;
typedef __attribute__((ext_vector_type(4))) int i32x4;
typedef __attribute__((ext_vector_type(4))) unsigned short u16x4;
typedef unsigned int u32;
typedef unsigned short u16;

__device__ __forceinline__ u16 f2bf(float f) {
    union { float f; u32 u; } v; v.f = f;
    u32 r = v.u + 0x7FFFu + ((v.u >> 16) & 1u);
    return (u16)(r >> 16);
}

// async global->LDS 16B: LDS dest wave-uniform base + lane*16; swizzle lives
// in the per-lane global source address (m104/m173 rule).
__device__ __forceinline__ void gl_lds16(const u16* g, u16* l) {
    __builtin_amdgcn_global_load_lds(
        (__attribute__((address_space(1))) void*)(uintptr_t)g,
        (__attribute__((address_space(3))) void*)l, 16, 0, 0);
}

// ---------------------------------------------------------------------------
// Kernel 0: Wt[o][c] = bf16(W_lin[c][o]).  16 blocks x 256 thr (tiny).
// ---------------------------------------------------------------------------
__global__ __launch_bounds__(256) void wt_kernel(
    const float* __restrict__ W_lin, u16* __restrict__ Wt)
{
    __shared__ float ws2[8][132];
    const int t = threadIdx.x, o0 = blockIdx.x * 8;
    // load W_lin[c][o0..o0+8): thread -> c = t>>1, o-chunk = t&1
    f32x4 v = *(const f32x4*)(W_lin + (t >> 1) * OO + o0 + (t & 1) * 4);
    #pragma unroll
    for (int e = 0; e < 4; ++e) ws2[(t & 1) * 4 + e][t >> 1] = v[e];
    __syncthreads();
    const int oo = t >> 5, c0 = (t & 31) * 4;
    f32x4 u = *(const f32x4*)&ws2[oo][c0];
    u16x4 h;
    #pragma unroll
    for (int e = 0; e < 4; ++e) h[e] = f2bf(u[e]);
    *(u16x4*)(Wt + (size_t)(o0 + oo) * CC + c0) = h;
}

// ---------------------------------------------------------------------------
// Kernel 1: precompute via MFMA, no LDS.
//   sj[b][n] = x[b][n]·w1 + b_fc ; sk[b][n] = x[b][n]·w2   (f32 dots)
//   Yt[b][o][k] = bf16((x @ W_lin)^T)  via mfma_16x16x32_bf16
// 512 blocks x 256 thr; k-tile 32 rows. Wave w: m-tile w&1, n-tiles (w>>1)*4..+4.
// ---------------------------------------------------------------------------
__global__ __launch_bounds__(256) void precompute_kernel(
    const float* __restrict__ x, const float* __restrict__ W_fc,
    const float* __restrict__ b_fc, const u16* __restrict__ Wt,
    float* __restrict__ sj, float* __restrict__ sk, u16* __restrict__ Yt)
{
    const int t = threadIdx.x, l = t & 63, w = t >> 6;
    const int sl = l & 15, g = l >> 4;
    const int b  = blockIdx.x >> 6;
    const int k0 = (blockIdx.x & 63) << 5;
    const int mt = w & 1, nb = (w >> 1) << 2;
    const int row = k0 + mt * 16 + sl;
    const float* xr = x + ((size_t)(b * NN + row) << 7);

    // A-fragments (bf16 from f32 x) + f32 sj/sk partial dots
    bf16x8 a[4];
    float p1 = 0.f, p2 = 0.f;
    #pragma unroll
    for (int ks = 0; ks < 4; ++ks) {
        f32x4 lo4 = *(const f32x4*)(xr + ks * 32 + g * 8);
        f32x4 hi4 = *(const f32x4*)(xr + ks * 32 + g * 8 + 4);
        f32x4 w1l = *(const f32x4*)(W_fc + ks * 32 + g * 8);
        f32x4 w1h = *(const f32x4*)(W_fc + ks * 32 + g * 8 + 4);
        f32x4 w2l = *(const f32x4*)(W_fc + CC + ks * 32 + g * 8);
        f32x4 w2h = *(const f32x4*)(W_fc + CC + ks * 32 + g * 8 + 4);
        bf16x8 av;
        #pragma unroll
        for (int e = 0; e < 4; ++e) {
            p1 += lo4[e] * w1l[e] + hi4[e] * w1h[e];
            p2 += lo4[e] * w2l[e] + hi4[e] * w2h[e];
            av[e]     = (short)f2bf(lo4[e]);
            av[e + 4] = (short)f2bf(hi4[e]);
        }
        a[ks] = av;
    }
    p1 += __shfl_xor(p1, 16); p1 += __shfl_xor(p1, 32);
    p2 += __shfl_xor(p2, 16); p2 += __shfl_xor(p2, 32);
    if (w < 2 && g == 0) {          // waves 0,1 own rows (dedup vs waves 2,3)
        sj[b * NN + row] = p1 + b_fc[0];
        sk[b * NN + row] = p2;
    }

    // Y-GEMM: 4 n-tiles x 4 k-steps = 16 MFMA per wave
    f32x4 acc[4];
    #pragma unroll
    for (int i = 0; i < 4; ++i) acc[i] = (f32x4){0.f, 0.f, 0.f, 0.f};
    #pragma unroll
    for (int i = 0; i < 4; ++i) {
        const u16* wp = Wt + (size_t)((nb + i) * 16 + sl) * CC;
        #pragma unroll
        for (int ks = 0; ks < 4; ++ks) {
            bf16x8 bv = *(const bf16x8*)(wp + ks * 32 + g * 8);
            acc[i] = __builtin_amdgcn_mfma_f32_16x16x32_bf16(a[ks], bv, acc[i], 0, 0, 0);
        }
    }
    // C layout: col=lane&15 (o), row=(lane>>4)*4+reg (k) -> 8B contiguous in k
    #pragma unroll
    for (int i = 0; i < 4; ++i) {
        const int o = (nb + i) * 16 + sl;
        u16x4 h;
        #pragma unroll
        for (int e = 0; e < 4; ++e) h[e] = f2bf(acc[i][e]);
        *(u16x4*)(Yt + (size_t)(b * OO + o) * NN + k0 + mt * 16 + g * 4) = h;
    }
}

// ---------------------------------------------------------------------------
// Kernel 2: main fused aggregation. Lane-contiguous adj loads, 2-deep adj/sk
// prefetch, counted vmcnt(18), double-buffered Y staging.
//   P[j][k] = adj ? sigmoid(sj[j]+sk[k]) : 0 (bf16); V = P@Y^T (MFMA);
//   out = V/rowsum + b_lin
// 512 blocks (b = bid&7 -> XCD-pinned), 256 thr / 4 waves; j-tile 32, K 128.
// VMEM/iter = 8 stage + 4 adj + 1 sk = 13; stage(kt) has 18 younger ops at
// the wait point -> vmcnt(18).
// ---------------------------------------------------------------------------
__global__ __launch_bounds__(256, 2) void graphconv_main(
    const int* __restrict__ adj, const float* __restrict__ sj,
    const float* __restrict__ sk, const u16* __restrict__ Yt,
    const float* __restrict__ b_lin, float* __restrict__ out)
{
    __shared__ __align__(16) u16 ybuf[2][16384];  // 2 x (128 o x 16 chunks x 8)
    __shared__ __align__(16) u16 pbuf[4096];      // 32 j x 16 chunks x 8
    __shared__ float Sld[32];

    const int t  = threadIdx.x;
    const int l  = t & 63, w = t >> 6;
    const int sw = l & 15, kg = l >> 4;
    const int lo = l & 31, hi = l >> 5;
    const int b  = blockIdx.x & 7;
    const int j0 = (blockIdx.x >> 3) << 5;

    // P-phase mapping: instr q covers rows w*8+2q+hi, lane-contiguous 16B
    const int* arow[4];
    float sjr[4];
    #pragma unroll
    for (int q = 0; q < 4; ++q) {
        const int R = j0 + w * 8 + 2 * q + hi;
        arow[q] = adj + ((size_t)b * NN + R) * NN + lo * 4;
        sjr[q]  = sj[b * NN + R];
    }
    const float* skp = sk + b * NN + lo * 4;

    // Y staging: linear LDS dest, inverse-swizzled per-lane global source
    u32 yoff[8];
    #pragma unroll
    for (int i = 0; i < 8; ++i) {
        int u  = (w * 8 + i) * 64 + l;
        int o  = u >> 4;
        int kc = (u & 15) ^ (o & 15);
        yoff[i] = (u32)(b * OO + o) * NN + kc * 8;
    }

    f32x4 acc[2][2];
    #pragma unroll
    for (int js = 0; js < 2; ++js)
        #pragma unroll
        for (int os = 0; os < 2; ++os) acc[js][os] = (f32x4){0.f, 0.f, 0.f, 0.f};
    float psum[4] = {0.f, 0.f, 0.f, 0.f};

    // prologue: stage(0) [8] + adj/sk(0) [5] + adj/sk(1) [5]
    #pragma unroll
    for (int i = 0; i < 8; ++i)
        gl_lds16(Yt + yoff[i], &ybuf[0][(w * 8 + i) * 512]);
    i32x4 a_cur[4], a_n1[4];
    f32x4 s_cur, s_n1;
    #pragma unroll
    for (int q = 0; q < 4; ++q) a_cur[q] = *(const i32x4*)(arow[q]);
    s_cur = *(const f32x4*)(skp);
    #pragma unroll
    for (int q = 0; q < 4; ++q) a_n1[q] = *(const i32x4*)(arow[q] + 128);
    s_n1 = *(const f32x4*)(skp + 128);

    for (int kt = 0; kt < 16; ++kt) {
        const int cur = kt & 1;
        const int kt1 = (kt < 15) ? kt + 1 : 15;  // tail re-stage: idempotent
        const int kt2 = (kt < 14) ? kt + 2 : 15;  // keeps vmcnt count uniform
        // stage next Y tile (in flight across this whole iteration)
        #pragma unroll
        for (int i = 0; i < 8; ++i)
            gl_lds16(Yt + yoff[i] + (kt1 << 7), &ybuf[cur ^ 1][(w * 8 + i) * 512]);
        // 2-deep adj/sk prefetch
        i32x4 a_n2[4]; f32x4 s_n2;
        #pragma unroll
        for (int q = 0; q < 4; ++q) a_n2[q] = *(const i32x4*)(arow[q] + kt2 * 128);
        s_n2 = *(const f32x4*)(skp + kt2 * 128);

        // P = masked sigmoid; per-thread rowsum accumulates in registers
        u16x4 hq[4];
        #pragma unroll
        for (int q = 0; q < 4; ++q) {
            #pragma unroll
            for (int e = 0; e < 4; ++e) {
                float z  = sjr[q] + s_cur[e];
                float sg = __builtin_amdgcn_rcpf(1.0f + __expf(-z));
                float pv = a_cur[q][e] ? sg : 0.0f;
                psum[q] += pv;
                hq[q][e] = f2bf(pv);
            }
        }
        {
            const int kc = lo >> 1, hh = lo & 1;
            #pragma unroll
            for (int q = 0; q < 4; ++q) {
                const int R = w * 8 + 2 * q + hi;
                const int u = R * 16 + (kc ^ (R & 15));
                *(u16x4*)&pbuf[u * 8 + hh * 4] = hq[q];
            }
        }

        // counted drain: stage(kt) complete, 18 younger ops stay in flight
        asm volatile("s_waitcnt vmcnt(18)" ::: "memory");
        asm volatile("s_waitcnt lgkmcnt(0)" ::: "memory");
        __builtin_amdgcn_s_barrier();
        asm volatile("" ::: "memory");

        // MFMA: wave w -> j 0..31 x o [w*32, w*32+32)
        #pragma unroll
        for (int kk = 0; kk < 4; ++kk) {
            const int kc = kk * 4 + kg;
            bf16x8 af[2], bfr[2];
            #pragma unroll
            for (int js = 0; js < 2; ++js)
                af[js] = *(const bf16x8*)&pbuf[((js * 16 + sw) * 16 + (kc ^ sw)) * 8];
            #pragma unroll
            for (int os = 0; os < 2; ++os) {
                int o = w * 32 + os * 16 + sw;
                bfr[os] = *(const bf16x8*)&ybuf[cur][(o * 16 + (kc ^ sw)) * 8];
            }
            #pragma unroll
            for (int js = 0; js < 2; ++js)
                #pragma unroll
                for (int os = 0; os < 2; ++os)
                    acc[js][os] = __builtin_amdgcn_mfma_f32_16x16x32_bf16(
                        af[js], bfr[os], acc[js][os], 0, 0, 0);
        }

        asm volatile("" ::: "memory");
        __builtin_amdgcn_s_barrier();   // MFMA LDS reads done before next writes
        asm volatile("" ::: "memory");

        #pragma unroll
        for (int q = 0; q < 4; ++q) a_cur[q] = a_n1[q];
        s_cur = s_n1;
        #pragma unroll
        for (int q = 0; q < 4; ++q) a_n1[q] = a_n2[q];
        s_n1 = s_n2;
    }

    // rowsum reduce (once): rows' 128 k live across 32 lanes (same hi)
    #pragma unroll
    for (int q = 0; q < 4; ++q) {
        float s = psum[q];
        s += __shfl_xor(s, 1); s += __shfl_xor(s, 2); s += __shfl_xor(s, 4);
        s += __shfl_xor(s, 8); s += __shfl_xor(s, 16);
        if (lo == 0) Sld[w * 8 + 2 * q + hi] = s;
    }
    __syncthreads();   // also drains tail junk DMA (vmcnt 0) before LDS reuse ends

    #pragma unroll
    for (int js = 0; js < 2; ++js) {
        float rinv[4];
        #pragma unroll
        for (int i = 0; i < 4; ++i) rinv[i] = 1.0f / Sld[js * 16 + kg * 4 + i];
        #pragma unroll
        for (int os = 0; os < 2; ++os) {
            const int col = w * 32 + os * 16 + sw;
            const float bl = b_lin[col];
            #pragma unroll
            for (int i = 0; i < 4; ++i) {
                size_t row = (size_t)(b * NN + j0 + js * 16 + kg * 4 + i);
                out[row * OO + col] = acc[js][os][i] * rinv[i] + bl;
            }
        }
    }
}

extern "C" void kernel_launch(void* const* d_in, const int* in_sizes, int n_in,
                              void* d_out, int out_size, void* d_ws, size_t ws_size,
                              hipStream_t stream) {
    const float* x     = (const float*)d_in[0];
    const int*   adj   = (const int*)d_in[1];
    const float* W_fc  = (const float*)d_in[2];
    const float* b_fc  = (const float*)d_in[3];
    const float* W_lin = (const float*)d_in[4];
    const float* b_lin = (const float*)d_in[5];
    float* out = (float*)d_out;

    // workspace: Yt (bf16, 4MB) | sj (64KB) | sk (64KB) | Wt (32KB)
    u16*   Yt = (u16*)d_ws;
    float* sj = (float*)((char*)d_ws + (size_t)BB * OO * NN * sizeof(u16));
    float* sk = sj + BB * NN;
    u16*   Wt = (u16*)(sk + BB * NN);

    wt_kernel<<<16, 256, 0, stream>>>(W_lin, Wt);
    precompute_kernel<<<512, 256, 0, stream>>>(x, W_fc, b_fc, Wt, sj, sk, Yt);
    graphconv_main<<<512, 256, 0, stream>>>(adj, sj, sk, Yt, b_lin, out);
}